// Round 6
// baseline (357.555 us; speedup 1.0000x reference)
//
#include <hip/hip_runtime.h>

#define NN 100000
#define EE 400000
#define STRIPS 6250          // NN/16, exact
#define STRIDE 1024          // waves per type: 256 blocks * 4 waves
#define MARK_BLOCKS 391      // ceil((EE/4)/256)

typedef unsigned short u16;
typedef __attribute__((ext_vector_type(4))) float floatx4;
typedef __attribute__((ext_vector_type(8))) short shortx8;
typedef __attribute__((ext_vector_type(4))) unsigned short ushortx4;
typedef __attribute__((ext_vector_type(8))) unsigned short ushortx8;

__device__ __forceinline__ u16 f2bf(float f) {
    unsigned u = __float_as_uint(f);
    u += 0x7FFFu + ((u >> 16) & 1u);
    return (u16)(u >> 16);
}

// ---- fused pre-pass: degree masks (idempotent byte stores, int4 edge reads)
//      + W -> bf16 MFMA-A-frag-order pre-pack into workspace
__global__ __launch_bounds__(256) void mark_conv(
    const int4* __restrict__ daa, const int4* __restrict__ dab,
    const int4* __restrict__ dba,
    const float* __restrict__ Wr0, const float* __restrict__ Wr1,
    unsigned char* __restrict__ m, u16* __restrict__ wbf) {
    const int blk = blockIdx.x;
    if (blk < MARK_BLOCKS) {
        int i = blk * 256 + threadIdx.x;
        if (i < EE / 4) {
            int4 a = daa[i], bb = dab[i], c = dba[i];
            m[a.x] = 1; m[a.y] = 1; m[a.z] = 1; m[a.w] = 1;
            m[NN + bb.x] = 1; m[NN + bb.y] = 1; m[NN + bb.z] = 1; m[NN + bb.w] = 1;
            m[2 * NN + c.x] = 1; m[2 * NN + c.y] = 1; m[2 * NN + c.z] = 1; m[2 * NN + c.w] = 1;
        }
    } else {
        // 32 blocks: 8192 threads, one ushortx8 (8 W values) each.
        // Layout matches fused2's af read: [type][mat][chunk 0..31][l2 0..63][j 0..7]
        int flat = (blk - MARK_BLOCKS) * 256 + threadIdx.x;  // [0, 8192)
        int type = flat >> 12;
        int mat = (flat >> 11) & 1;
        int chunk = (flat >> 6) & 31;
        int l2 = flat & 63;
        int kbase = (chunk >> 3) * 32 + (l2 >> 4) * 8;
        int n = (chunk & 7) * 16 + (l2 & 15);
        const float* W = (mat ? Wr1 : Wr0) + type * 16384;
        ushortx8 p;
#pragma unroll
        for (int j = 0; j < 8; ++j) p[j] = f2bf(W[(kbase + j) * 128 + n]);
        *(ushortx8*)&wbf[((type * 2 + mat) << 14) + chunk * 512 + l2 * 8] = p;
    }
}

// ---- persistent fused 2-layer, STATIC strips + DEPTH-2 prefetch ping-pong.
// out[m] = relu(s^2*(z@W1) + s*b1), z = relu(feat@W0 + b0)   [relu(s*x)=s*relu(x)]
// Transposed MFMA form D = W^T x feat^T (layouts HW-verified).
// 256 thr (4 waves), 80 KB LDS -> 2 blocks/CU, 8 waves/CU, direct 64B stores.
//
// ROUND-5 POST-MORTEM: the atomic work queue globally serialized the kernel —
// 12.5K same-line device-scope atomics at ~23 ns each (cross-XCD line
// ping-pong) = the whole 143 µs. Per-wave latency hiding cannot hide a
// machine-level throughput serialization. Static assignment restored; the
// 15% pigeonhole tail is far cheaper than the atomic floor.
// ROUND-0 LIMITER: 27% HBM, all pipes idle = latency-bound at prefetch
// depth 1 (~8 KB in flight/wave; compute phase ~0.5 µs < loaded HBM latency).
// FIX: depth-2 ping-pong (pf0/pf1, statically indexed via twice-called
// inlined lambda) -> each load gets TWO iterations to complete.
__global__ __launch_bounds__(256, 2) void fused2(
    const float* __restrict__ featA, const float* __restrict__ featB,
    const u16* __restrict__ wbf,
    const float* __restrict__ br0, const float* __restrict__ br1,
    const unsigned char* __restrict__ masks, float* __restrict__ out) {
    __shared__ u16 lds[40960];   // 80 KB: [W0f 16384][W1f 16384][h1: 4 waves x 2048]

    const int type = blockIdx.x >> 8;           // 256 blocks per type
    const int bid = blockIdx.x & 255;
    const float* feat = type ? featB : featA;
    const float* b0 = br0 + type * 128;
    const float* b1 = br1 + type * 128;
    float* outp = out + (size_t)type * NN * 128;

    const int t = threadIdx.x;
    const int wave = t >> 6, lane = t & 63;
    const int quad = lane >> 4, mrow = lane & 15;
    const int gw = bid * 4 + wave;              // [0, 1024)

    // ---- bias fragments, loaded ONCE (per-lane constants under C-layout)
    floatx4 b0f[8], b1f[8];
#pragma unroll
    for (int nt = 0; nt < 8; ++nt) {
        b0f[nt] = *(const floatx4*)(b0 + nt * 16 + quad * 4);
        b1f[nt] = *(const floatx4*)(b1 + nt * 16 + quad * 4);
    }

    // ---- depth-2 prefetch: strip gw -> pf0, strip gw+STRIDE -> pf1
    //      (gw+STRIDE <= 2047 < STRIPS always; issued BEFORE staging barrier)
    int s = gw;
    floatx4 pf0[8], pf1[8];
    unsigned char pa0 = 0, pb0 = 0, pa1 = 0, pb1 = 0;
    {
        const float* arow = feat + (size_t)(s * 16 + mrow) * 128;
#pragma unroll
        for (int ks = 0; ks < 4; ++ks) {
            pf0[2 * ks]     = *(const floatx4*)(arow + ks * 32 + quad * 8);
            pf0[2 * ks + 1] = *(const floatx4*)(arow + ks * 32 + quad * 8 + 4);
        }
        int row = s * 16 + mrow;
        if (type) pa0 = masks[NN + row];
        else { pa0 = masks[row]; pb0 = masks[2 * NN + row]; }
    }
    {
        const float* arow = feat + (size_t)((s + STRIDE) * 16 + mrow) * 128;
#pragma unroll
        for (int ks = 0; ks < 4; ++ks) {
            pf1[2 * ks]     = *(const floatx4*)(arow + ks * 32 + quad * 8);
            pf1[2 * ks + 1] = *(const floatx4*)(arow + ks * 32 + quad * 8 + 4);
        }
        int row = (s + STRIDE) * 16 + mrow;
        if (type) pa1 = masks[NN + row];
        else { pa1 = masks[row]; pb1 = masks[2 * NN + row]; }
    }

    // ---- stage pre-packed W0f|W1f: 64 KB linear coalesced copy, 16 x 16B/thread
    {
        const ushortx8* __restrict__ wsrc = (const ushortx8*)(wbf + ((size_t)type << 15));
#pragma unroll
        for (int i = 0; i < 16; ++i) {
            int idx = i * 256 + t;              // [0, 4096) 16B chunks
            *(ushortx8*)&lds[idx * 8] = wsrc[idx];
        }
    }
    __syncthreads();   // the only barrier

    const int h1base = 32768 + wave * 2048;

    // one full strip: consume PF -> bfrag, re-issue PF for s+2*STRIDE,
    // GEMM1 -> h1 -> GEMM2 -> store. Statically specialized per buffer.
    auto strip_body = [&](floatx4 (&PF)[8], unsigned char& PM0, unsigned char& PM1) {
        // consume prefetch first (PF is overwritten by the re-issue below)
        shortx8 bfrag[4];
#pragma unroll
        for (int ks = 0; ks < 4; ++ks) {
            floatx4 f0 = PF[2 * ks], f1 = PF[2 * ks + 1];
            union { shortx8 v; u16 u[8]; } uu;
            uu.u[0] = f2bf(f0[0]); uu.u[1] = f2bf(f0[1]);
            uu.u[2] = f2bf(f0[2]); uu.u[3] = f2bf(f0[3]);
            uu.u[4] = f2bf(f1[0]); uu.u[5] = f2bf(f1[1]);
            uu.u[6] = f2bf(f1[2]); uu.u[7] = f2bf(f1[3]);
            bfrag[ks] = uu.v;
        }
        const float scl = type ? (1.0f + (float)PM0) * 0.5f
                               : (1.0f + (float)PM0 + (float)PM1) * (1.0f / 3.0f);
        const float sq = scl * scl;
        const int row = s * 16 + mrow;

        // re-issue this buffer for strip s+2*STRIDE (two iterations to land)
        const int spre = s + 2 * STRIDE;
        if (spre < STRIPS) {
            const float* arow = feat + (size_t)(spre * 16 + mrow) * 128;
#pragma unroll
            for (int ks = 0; ks < 4; ++ks) {
                PF[2 * ks]     = *(const floatx4*)(arow + ks * 32 + quad * 8);
                PF[2 * ks + 1] = *(const floatx4*)(arow + ks * 32 + quad * 8 + 4);
            }
            int nrow = spre * 16 + mrow;
            if (type) PM0 = masks[NN + nrow];
            else { PM0 = masks[nrow]; PM1 = masks[2 * NN + nrow]; }
        }

        // GEMM1: acc[nt] = W0^T tile(nt) x feat^T, acc init = b0 (bias free)
        floatx4 acc[8];
#pragma unroll
        for (int nt = 0; nt < 8; ++nt) acc[nt] = b0f[nt];
#pragma unroll
        for (int ks = 0; ks < 4; ++ks)
#pragma unroll
            for (int nt = 0; nt < 8; ++nt) {
                shortx8 af = *(const shortx8*)&lds[((ks * 8 + nt) << 9) + lane * 8];
                acc[nt] = __builtin_amdgcn_mfma_f32_16x16x32_bf16(af, bfrag[ks], acc[nt], 0, 0, 0);
            }

        // epilogue1: z = relu(acc), wave-private h1 in GEMM2 B-frag order
#pragma unroll
        for (int nt = 0; nt < 8; ++nt) {
            ushortx4 p;
#pragma unroll
            for (int r = 0; r < 4; ++r)
                p[r] = f2bf(fmaxf(acc[nt][r], 0.0f));
            int q2 = (2 * nt + (quad >> 1)) & 3;
            *(ushortx4*)&lds[h1base + (nt >> 1) * 512 + q2 * 128 + mrow * 8 + (quad & 1) * 4] = p;
        }

        shortx8 h1b[4];
#pragma unroll
        for (int ks = 0; ks < 4; ++ks)
            h1b[ks] = *(const shortx8*)&lds[h1base + ks * 512 + lane * 8];

        // GEMM2: acc2[nt] = W1^T tile(nt) x z^T
        floatx4 acc2[8];
#pragma unroll
        for (int nt = 0; nt < 8; ++nt) acc2[nt] = (floatx4){0.f, 0.f, 0.f, 0.f};
#pragma unroll
        for (int ks = 0; ks < 4; ++ks)
#pragma unroll
            for (int nt = 0; nt < 8; ++nt) {
                shortx8 af = *(const shortx8*)&lds[16384 + ((ks * 8 + nt) << 9) + lane * 8];
                acc2[nt] = __builtin_amdgcn_mfma_f32_16x16x32_bf16(af, h1b[ks], acc2[nt], 0, 0, 0);
            }

        // epilogue2: out = relu(s^2*acc2 + s*b1), direct 64B stores
        float* orow = outp + (size_t)row * 128;
#pragma unroll
        for (int nt = 0; nt < 8; ++nt) {
            floatx4 o;
#pragma unroll
            for (int r = 0; r < 4; ++r)
                o[r] = fmaxf(sq * acc2[nt][r] + scl * b1f[nt][r], 0.0f);
            *(floatx4*)(orow + nt * 16 + quad * 4) = o;
        }
    };

    for (;;) {
        strip_body(pf0, pa0, pb0);              // strip s (even ordinal)
        if (s + STRIDE >= STRIPS) break;
        s += STRIDE;
        strip_body(pf1, pa1, pb1);              // strip s (odd ordinal)
        if (s + STRIDE >= STRIPS) break;
        s += STRIDE;
    }
}

extern "C" void kernel_launch(void* const* d_in, const int* in_sizes, int n_in,
                              void* d_out, int out_size, void* d_ws, size_t ws_size,
                              hipStream_t stream) {
    (void)in_sizes; (void)n_in; (void)out_size; (void)ws_size;
    const float* featA = (const float*)d_in[0];
    const float* featB = (const float*)d_in[1];
    const int* dst_aa = (const int*)d_in[3];
    const int* dst_ab = (const int*)d_in[5];
    const int* dst_ba = (const int*)d_in[7];
    const float* Wr0 = (const float*)d_in[10];
    const float* br0 = (const float*)d_in[11];
    const float* Wr1 = (const float*)d_in[16];
    const float* br1 = (const float*)d_in[17];

    unsigned char* masks = (unsigned char*)d_ws;              // 3*NN bytes
    u16* wbf = (u16*)((char*)d_ws + (size_t)3 * NN);          // 131072 B (300000 % 16 == 0)

    hipMemsetAsync(masks, 0, (size_t)3 * NN, stream);
    mark_conv<<<MARK_BLOCKS + 32, 256, 0, stream>>>(
        (const int4*)dst_aa, (const int4*)dst_ab, (const int4*)dst_ba,
        Wr0, Wr1, masks, wbf);
    fused2<<<512, 256, 0, stream>>>(featA, featB, wbf, br0, br1,
                                    masks, (float*)d_out);
}